// Round 1
// baseline (9384.186 us; speedup 1.0000x reference)
//
#include <hip/hip_runtime.h>
#include <hip/hip_bf16.h>
#include <math.h>

#define L_SEQ 64
#define B_SZ  64
#define DEMB  128
#define DENC  256
#define DDEC  512
#define NHD   8
#define HDIM  64
#define VSZ   32000
#define TDEC  32

typedef unsigned long long ull;

__device__ __forceinline__ float sigm(float x){ return 1.0f/(1.0f+expf(-x)); }
__device__ __forceinline__ int rfl(int x){ return __builtin_amdgcn_readfirstlane(x); }
__device__ __forceinline__ unsigned fmono(float f){
    unsigned u = __float_as_uint(f);
    return (u & 0x80000000u) ? ~u : (u | 0x80000000u);
}

// ---------------- init: zero encoder state, xeT = start_emb ----------------
__global__ void k_init(float* hTe, float* cTe, float* xeT, const float* start_emb){
    int i = blockIdx.x*256 + threadIdx.x;
    int stride = gridDim.x*256;
    for (int j = i; j < 2*2*DENC*B_SZ; j += stride) hTe[j] = 0.f;
    for (int j = i; j < 2*DENC*B_SZ;   j += stride) cTe[j] = 0.f;
    for (int j = i; j < DEMB*B_SZ;     j += stride) xeT[j] = start_emb[j >> 6];
}

// ---------------- embedding: xT[t][k][b] = tok_emb[nx[b][t]][k] ----------------
__global__ void k_embed(const int* nx, const float* tok_emb, float* xT){
    int t = blockIdx.x;
    for (int j = threadIdx.x; j < B_SZ*DEMB; j += 256){
        int b = j >> 7; int k = j & 127;
        int row = nx[b*L_SEQ + t];
        xT[(t*DEMB + k)*B_SZ + b] = tok_emb[(size_t)row*DEMB + k];
    }
}

// ---------------- encoder input pre-gates: GpreT[dir][t][row][b] ----------------
__global__ void k_pregates(const float* xT, const float* Wf, const float* bf,
                           const float* Wb, const float* bb, float* GpreT){
    int wid  = (blockIdx.x*256 + threadIdx.x) >> 6;
    int lane = threadIdx.x & 63;
    for (int job = wid; job < 2*L_SEQ*1024; job += 2048){
        int dir = rfl(job >> 16);
        int rem = job & 65535;
        int t   = rfl(rem >> 10);
        int row = rfl(rem & 1023);
        const float* W = dir ? Wb : Wf;
        float acc = (dir ? bb : bf)[row];
        const float4* W4 = (const float4*)(W + (size_t)row*DEMB);
        const float* xr = xT + (size_t)t*DEMB*B_SZ + lane;
        #pragma unroll 4
        for (int k4 = 0; k4 < DEMB/4; ++k4){
            float4 w = W4[k4];
            const float* hp = xr + k4*4*B_SZ;
            acc += w.x*hp[0] + w.y*hp[B_SZ] + w.z*hp[2*B_SZ] + w.w*hp[3*B_SZ];
        }
        GpreT[(size_t)job*B_SZ + lane] = acc;
    }
}

// ---------------- one encoder LSTM step (both directions) ----------------
__global__ void k_enc_step(int s, const float* __restrict__ GpreT,
                           const float* __restrict__ Whh_f, const float* __restrict__ Whh_b,
                           float* hTe, float* cTe, float* memT){
    int wid  = blockIdx.x;              // 512 blocks x 64 threads
    int lane = threadIdx.x & 63;
    int dir = rfl(wid >> 8);
    int u   = rfl(wid & 255);
    int tpre = dir ? (63 - s) : s;
    const float* Gp = GpreT + (size_t)(dir*L_SEQ + tpre)*1024*B_SZ;
    float gi = Gp[(u      )*B_SZ + lane];
    float gf = Gp[(u + 256)*B_SZ + lane];
    float gg = Gp[(u + 512)*B_SZ + lane];
    float go = Gp[(u + 768)*B_SZ + lane];
    const float* hT  = hTe + (size_t)(s&1)*(2*DENC*B_SZ) + dir*DENC*B_SZ;
    float*       hTn = hTe + (size_t)((s+1)&1)*(2*DENC*B_SZ) + dir*DENC*B_SZ;
    const float* W = dir ? Whh_b : Whh_f;
    const float4* Wi = (const float4*)(W + (size_t)(u      )*DENC);
    const float4* Wf = (const float4*)(W + (size_t)(u + 256)*DENC);
    const float4* Wg = (const float4*)(W + (size_t)(u + 512)*DENC);
    const float4* Wo = (const float4*)(W + (size_t)(u + 768)*DENC);
    #pragma unroll 4
    for (int k4 = 0; k4 < DENC/4; ++k4){
        float4 wi = Wi[k4], wf = Wf[k4], wg = Wg[k4], wo = Wo[k4];
        const float* hp = hT + k4*4*B_SZ + lane;
        float h0 = hp[0], h1 = hp[B_SZ], h2 = hp[2*B_SZ], h3 = hp[3*B_SZ];
        gi += wi.x*h0 + wi.y*h1 + wi.z*h2 + wi.w*h3;
        gf += wf.x*h0 + wf.y*h1 + wf.z*h2 + wf.w*h3;
        gg += wg.x*h0 + wg.y*h1 + wg.z*h2 + wg.w*h3;
        go += wo.x*h0 + wo.y*h1 + wo.z*h2 + wo.w*h3;
    }
    float c  = cTe[(dir*DENC + u)*B_SZ + lane];
    float cn = sigm(gf)*c + sigm(gi)*tanhf(gg);
    float hn = sigm(go)*tanhf(cn);
    cTe[(dir*DENC + u)*B_SZ + lane] = cn;
    hTn[u*B_SZ + lane] = hn;
    int tmem = dir ? (63 - s) : s;
    memT[((size_t)tmem*DDEC + dir*DENC + u)*B_SZ + lane] = hn;
}

// ---------------- h0 = tanh(cat(hf,hb) @ transfer_W^T);  c0 = style_emb[label] ----------------
__global__ void k_h0(const float* hTe, const float* transfer_W, const float* style_emb,
                     const int* label, float* hTd, float* cTd){
    int u    = rfl((int)blockIdx.x);    // 512 blocks x 64 threads
    int lane = threadIdx.x & 63;
    const float* hf = hTe;                    // buf0 dir0 (final fwd h)
    const float* hb = hTe + DENC*B_SZ;        // buf0 dir1 (final bwd h)
    float acc = 0.f;
    const float4* W4 = (const float4*)(transfer_W + (size_t)u*DDEC);
    #pragma unroll 4
    for (int k4 = 0; k4 < 64; ++k4){
        float4 w = W4[k4];
        const float* hp = hf + k4*4*B_SZ + lane;
        acc += w.x*hp[0] + w.y*hp[B_SZ] + w.z*hp[2*B_SZ] + w.w*hp[3*B_SZ];
    }
    #pragma unroll 4
    for (int k4 = 64; k4 < 128; ++k4){
        float4 w = W4[k4];
        const float* hp = hb + (k4-64)*4*B_SZ + lane;
        acc += w.x*hp[0] + w.y*hp[B_SZ] + w.z*hp[2*B_SZ] + w.w*hp[3*B_SZ];
    }
    hTd[u*B_SZ + lane] = tanhf(acc);
    cTd[u*B_SZ + lane] = style_emb[(size_t)label[lane]*DDEC + u];
}

// ---------------- K/V precompute:  kT[b][h][d][l],  vv[b][h][l][d] ----------------
__global__ void k_kv(const float* memT, const float* attn_in_w, const float* attn_in_b,
                     float* kT, float* vv){
    int wid  = (blockIdx.x*256 + threadIdx.x) >> 6;
    int lane = threadIdx.x & 63;
    for (int job = wid; job < L_SEQ*1024; job += 2048){
        int t   = rfl(job >> 10);
        int row = rfl(job & 1023);
        int wrow = 512 + row;   // rows 512..1535 of attn_in_w are Wk;Wv
        const float4* W4 = (const float4*)(attn_in_w + (size_t)wrow*DDEC);
        float acc = attn_in_b[wrow];
        const float* mp = memT + (size_t)t*DDEC*B_SZ + lane;
        #pragma unroll 4
        for (int k4 = 0; k4 < 128; ++k4){
            float4 w = W4[k4];
            const float* hp = mp + k4*4*B_SZ;
            acc += w.x*hp[0] + w.y*hp[B_SZ] + w.z*hp[2*B_SZ] + w.w*hp[3*B_SZ];
        }
        if (row < 512){
            int h = row >> 6, d = row & 63;
            kT[(((size_t)lane*NHD + h)*HDIM + d)*L_SEQ + t] = acc;
        } else {
            int r2 = row - 512; int h = r2 >> 6, d = r2 & 63;
            vv[(((size_t)lane*NHD + h)*L_SEQ + t)*HDIM + d] = acc;
        }
    }
}

// ---------------- decoder LSTM cell (gates + state) ----------------
__global__ void k_gates(const float* __restrict__ xeT, const float* __restrict__ hTd, float* cTd,
                        const float* __restrict__ Wih, const float* __restrict__ Whh,
                        const float* __restrict__ bias, float* h_row){
    int u    = rfl((int)blockIdx.x);    // 512 blocks x 64 threads
    int lane = threadIdx.x & 63;
    float gi = bias[u], gf = bias[u+512], gg = bias[u+1024], go = bias[u+1536];
    {
        const float4* Wi = (const float4*)(Wih + (size_t)(u       )*DEMB);
        const float4* Wf = (const float4*)(Wih + (size_t)(u + 512 )*DEMB);
        const float4* Wg = (const float4*)(Wih + (size_t)(u + 1024)*DEMB);
        const float4* Wo = (const float4*)(Wih + (size_t)(u + 1536)*DEMB);
        #pragma unroll 4
        for (int k4 = 0; k4 < DEMB/4; ++k4){
            float4 wi = Wi[k4], wf = Wf[k4], wg = Wg[k4], wo = Wo[k4];
            const float* hp = xeT + k4*4*B_SZ + lane;
            float h0 = hp[0], h1 = hp[B_SZ], h2 = hp[2*B_SZ], h3 = hp[3*B_SZ];
            gi += wi.x*h0 + wi.y*h1 + wi.z*h2 + wi.w*h3;
            gf += wf.x*h0 + wf.y*h1 + wf.z*h2 + wf.w*h3;
            gg += wg.x*h0 + wg.y*h1 + wg.z*h2 + wg.w*h3;
            go += wo.x*h0 + wo.y*h1 + wo.z*h2 + wo.w*h3;
        }
    }
    {
        const float4* Wi = (const float4*)(Whh + (size_t)(u       )*DDEC);
        const float4* Wf = (const float4*)(Whh + (size_t)(u + 512 )*DDEC);
        const float4* Wg = (const float4*)(Whh + (size_t)(u + 1024)*DDEC);
        const float4* Wo = (const float4*)(Whh + (size_t)(u + 1536)*DDEC);
        #pragma unroll 4
        for (int k4 = 0; k4 < DDEC/4; ++k4){
            float4 wi = Wi[k4], wf = Wf[k4], wg = Wg[k4], wo = Wo[k4];
            const float* hp = hTd + k4*4*B_SZ + lane;
            float h0 = hp[0], h1 = hp[B_SZ], h2 = hp[2*B_SZ], h3 = hp[3*B_SZ];
            gi += wi.x*h0 + wi.y*h1 + wi.z*h2 + wi.w*h3;
            gf += wf.x*h0 + wf.y*h1 + wf.z*h2 + wf.w*h3;
            gg += wg.x*h0 + wg.y*h1 + wg.z*h2 + wg.w*h3;
            go += wo.x*h0 + wo.y*h1 + wo.z*h2 + wo.w*h3;
        }
    }
    float c  = cTd[u*B_SZ + lane];
    float cn = sigm(gf)*c + sigm(gi)*tanhf(gg);
    float h_ = sigm(go)*tanhf(cn);
    cTd[u*B_SZ + lane] = cn;
    h_row[(size_t)lane*DDEC + u] = h_;
}

// ---------------- attention + output proj + residual + LayerNorm (one WG per batch) ----------------
__global__ void __launch_bounds__(256) k_attn(
        const float* __restrict__ h_row, const float* __restrict__ kT, const float* __restrict__ vv,
        const float* __restrict__ attn_in_w, const float* __restrict__ attn_in_b,
        const float* __restrict__ attn_out_w, const float* __restrict__ attn_out_b,
        const float* __restrict__ ln_g, const float* __restrict__ ln_b,
        float* hTd, float* hLN_row){
    int b = blockIdx.x, tid = threadIdx.x;
    __shared__ float hs[512], qs[512], ss[512], cx[512], ys[512];
    __shared__ float ssum[8];
    __shared__ float red[256];
    hs[tid]     = h_row[(size_t)b*512 + tid];
    hs[tid+256] = h_row[(size_t)b*512 + tid + 256];
    __syncthreads();
    // q = (h_ @ Wq^T + bq) * scale
    for (int r = 0; r < 2; ++r){
        int row = tid + r*256;
        float acc = attn_in_b[row];
        const float4* W4 = (const float4*)(attn_in_w + (size_t)row*512);
        #pragma unroll 4
        for (int k4 = 0; k4 < 128; ++k4){
            float4 w = W4[k4];
            acc += w.x*hs[k4*4] + w.y*hs[k4*4+1] + w.z*hs[k4*4+2] + w.w*hs[k4*4+3];
        }
        qs[row] = acc * 0.125f;
    }
    __syncthreads();
    // scores[h][l] = q[h]·k[l]
    for (int r = 0; r < 2; ++r){
        int job = tid + r*256; int h = job >> 6, l = job & 63;
        const float* kp = kT + ((size_t)b*NHD + h)*HDIM*L_SEQ + l;
        float acc = 0.f;
        #pragma unroll 8
        for (int d = 0; d < 64; ++d) acc += qs[h*64 + d] * kp[d*64];
        ss[job] = acc;
    }
    __syncthreads();
    if (tid < 8){
        float m = -1e30f;
        for (int l = 0; l < 64; ++l) m = fmaxf(m, ss[tid*64 + l]);
        float s = 0.f;
        for (int l = 0; l < 64; ++l){ float e = expf(ss[tid*64 + l] - m); ss[tid*64 + l] = e; s += e; }
        ssum[tid] = s;
    }
    __syncthreads();
    // ctx[h][d] = sum_l att * v
    for (int r = 0; r < 2; ++r){
        int job = tid + r*256; int h = job >> 6, d = job & 63;
        const float* vp = vv + ((size_t)b*NHD + h)*L_SEQ*HDIM + d;
        float acc = 0.f;
        #pragma unroll 8
        for (int l = 0; l < 64; ++l) acc += ss[h*64 + l] * vp[l*HDIM];
        cx[job] = acc / ssum[h];
    }
    __syncthreads();
    // a = ctx @ attn_out^T + b ; y = h_ + a
    for (int r = 0; r < 2; ++r){
        int row = tid + r*256;
        float acc = attn_out_b[row];
        const float4* W4 = (const float4*)(attn_out_w + (size_t)row*512);
        #pragma unroll 4
        for (int k4 = 0; k4 < 128; ++k4){
            float4 w = W4[k4];
            acc += w.x*cx[k4*4] + w.y*cx[k4*4+1] + w.z*cx[k4*4+2] + w.w*cx[k4*4+3];
        }
        ys[row] = hs[row] + acc;
    }
    __syncthreads();
    // LayerNorm
    red[tid] = ys[tid] + ys[tid+256];
    __syncthreads();
    for (int off = 128; off > 0; off >>= 1){ if (tid < off) red[tid] += red[tid+off]; __syncthreads(); }
    float mu = red[0] * (1.f/512.f);
    __syncthreads();
    float d0 = ys[tid] - mu, d1 = ys[tid+256] - mu;
    red[tid] = d0*d0 + d1*d1;
    __syncthreads();
    for (int off = 128; off > 0; off >>= 1){ if (tid < off) red[tid] += red[tid+off]; __syncthreads(); }
    float rstd = 1.f / sqrtf(red[0]*(1.f/512.f) + 1e-5f);
    for (int r = 0; r < 2; ++r){
        int i = tid + r*256;
        float hv = (ys[i] - mu) * rstd * ln_g[i] + ln_b[i];
        hLN_row[(size_t)b*512 + i] = hv;
        hTd[(size_t)i*64 + b] = hv;
    }
}

// ---------------- projection: logits = h @ proj_W^T + b ; per-wave argmax partials ----------------
__global__ void __launch_bounds__(256) k_proj(int t, const float* __restrict__ hTd,
                       const float* __restrict__ proj_W, const float* __restrict__ proj_b,
                       float* __restrict__ out, ull* __restrict__ partials){
    int wid  = (blockIdx.x*256 + threadIdx.x) >> 6;   // 0..1999, wave owns 16 vocab rows
    int lane = threadIdx.x & 63;                      // lane = batch
    int n0 = rfl(wid << 4);
    float acc[16];
    #pragma unroll
    for (int j = 0; j < 16; ++j) acc[j] = proj_b[n0 + j];
    const float* W = proj_W + (size_t)n0*DDEC;
    #pragma unroll 2
    for (int k4 = 0; k4 < 128; ++k4){
        float h0 = hTd[(k4*4+0)*B_SZ + lane];
        float h1 = hTd[(k4*4+1)*B_SZ + lane];
        float h2 = hTd[(k4*4+2)*B_SZ + lane];
        float h3 = hTd[(k4*4+3)*B_SZ + lane];
        #pragma unroll
        for (int j = 0; j < 16; ++j){
            float4 w = *(const float4*)(W + (size_t)j*DDEC + k4*4);
            acc[j] += w.x*h0 + w.y*h1 + w.z*h2 + w.w*h3;
        }
    }
    ull m = 0;
    float* op = out + (size_t)lane*(TDEC*VSZ) + (size_t)t*VSZ + n0;
    #pragma unroll
    for (int j = 0; j < 16; ++j){
        op[j] = acc[j];
        ull p = ((ull)fmono(acc[j]) << 32) | (unsigned)(~(unsigned)(n0 + j));
        m = (p > m) ? p : m;
    }
    partials[(size_t)lane*2048 + wid] = m;
}

// ---------------- argmax finalize + greedy-feedback embedding: xeT[k][b] ----------------
__global__ void k_fin(const ull* __restrict__ partials, const float* __restrict__ tok_emb, float* xeT){
    int b = blockIdx.x, tid = threadIdx.x;   // 128 threads
    __shared__ ull red[128];
    __shared__ int sidx;
    ull m = 0;
    for (int j = tid; j < 2000; j += 128){
        ull p = partials[(size_t)b*2048 + j];
        if (p > m) m = p;
    }
    red[tid] = m; __syncthreads();
    for (int off = 64; off > 0; off >>= 1){
        if (tid < off){ if (red[tid+off] > red[tid]) red[tid] = red[tid+off]; }
        __syncthreads();
    }
    if (tid == 0) sidx = (int)(~(unsigned)(red[0] & 0xffffffffull));
    __syncthreads();
    int idx = sidx;
    xeT[tid*B_SZ + b] = tok_emb[(size_t)idx*DEMB + tid];
}

extern "C" void kernel_launch(void* const* d_in, const int* in_sizes, int n_in,
                              void* d_out, int out_size, void* d_ws, size_t ws_size,
                              hipStream_t stream){
    (void)in_sizes; (void)n_in; (void)out_size; (void)ws_size;
    const int*   nx        = (const int*)d_in[0];
    const int*   label     = (const int*)d_in[1];
    const float* start_emb = (const float*)d_in[2];
    const float* tok_emb   = (const float*)d_in[3];
    const float* style_emb = (const float*)d_in[4];
    const float* enc_Wih_f = (const float*)d_in[5];
    const float* enc_Whh_f = (const float*)d_in[6];
    const float* enc_b_f   = (const float*)d_in[7];
    const float* enc_Wih_b = (const float*)d_in[8];
    const float* enc_Whh_b = (const float*)d_in[9];
    const float* enc_b_b   = (const float*)d_in[10];
    const float* transfer_W= (const float*)d_in[11];
    const float* dec_Wih   = (const float*)d_in[12];
    const float* dec_Whh   = (const float*)d_in[13];
    const float* dec_b     = (const float*)d_in[14];
    const float* attn_in_w = (const float*)d_in[15];
    const float* attn_in_b = (const float*)d_in[16];
    const float* attn_out_w= (const float*)d_in[17];
    const float* attn_out_b= (const float*)d_in[18];
    const float* proj_W    = (const float*)d_in[19];
    const float* proj_b    = (const float*)d_in[20];
    const float* ln_g      = (const float*)d_in[21];
    const float* ln_b      = (const float*)d_in[22];
    float* out = (float*)d_out;
    float* ws  = (float*)d_ws;

    size_t off = 0;
    float* xT    = ws + off; off += (size_t)L_SEQ*DEMB*B_SZ;        // 524288
    float* GpreT = ws + off; off += (size_t)2*L_SEQ*1024*B_SZ;      // 8388608
    float* memT  = ws + off; off += (size_t)L_SEQ*DDEC*B_SZ;        // 2097152
    float* kT    = ws + off; off += (size_t)B_SZ*NHD*HDIM*L_SEQ;    // 2097152
    float* vv    = ws + off; off += (size_t)B_SZ*NHD*L_SEQ*HDIM;    // 2097152
    float* hTe   = ws + off; off += 2*2*DENC*B_SZ;
    float* cTe   = ws + off; off += 2*DENC*B_SZ;
    float* hTd   = ws + off; off += DDEC*B_SZ;
    float* cTd   = ws + off; off += DDEC*B_SZ;
    float* h_row = ws + off; off += B_SZ*DDEC;
    float* hLN   = ws + off; off += B_SZ*DDEC;
    float* xeT   = ws + off; off += DEMB*B_SZ;
    ull* partials = (ull*)(ws + off); off += (size_t)B_SZ*2048*2;

    k_init<<<64, 256, 0, stream>>>(hTe, cTe, xeT, start_emb);
    k_embed<<<64, 256, 0, stream>>>(nx, tok_emb, xT);
    k_pregates<<<512, 256, 0, stream>>>(xT, enc_Wih_f, enc_b_f, enc_Wih_b, enc_b_b, GpreT);
    for (int s = 0; s < 64; ++s)
        k_enc_step<<<512, 64, 0, stream>>>(s, GpreT, enc_Whh_f, enc_Whh_b, hTe, cTe, memT);
    k_h0<<<512, 64, 0, stream>>>(hTe, transfer_W, style_emb, label, hTd, cTd);
    k_kv<<<512, 256, 0, stream>>>(memT, attn_in_w, attn_in_b, kT, vv);
    for (int t = 0; t < 32; ++t){
        k_gates<<<512, 64, 0, stream>>>(xeT, hTd, cTd, dec_Wih, dec_Whh, dec_b, h_row);
        k_attn<<<64, 256, 0, stream>>>(h_row, kT, vv, attn_in_w, attn_in_b,
                                       attn_out_w, attn_out_b, ln_g, ln_b, hTd, hLN);
        k_proj<<<500, 256, 0, stream>>>(t, hTd, proj_W, proj_b, out, partials);
        k_fin<<<64, 128, 0, stream>>>(partials, tok_emb, xeT);
    }
}

// Round 3
// 8529.089 us; speedup vs baseline: 1.1003x; 1.1003x over previous
//
#include <hip/hip_runtime.h>
#include <hip/hip_bf16.h>
#include <math.h>

#define L_SEQ 64
#define B_SZ  64
#define DEMB  128
#define DENC  256
#define DDEC  512
#define NHD   8
#define HDIM  64
#define VSZ   32000
#define TDEC  32

typedef unsigned long long ull;

__device__ __forceinline__ float sigm(float x){ return 1.0f/(1.0f+expf(-x)); }
__device__ __forceinline__ int rfl(int x){ return __builtin_amdgcn_readfirstlane(x); }
__device__ __forceinline__ unsigned fmono(float f){
    unsigned u = __float_as_uint(f);
    return (u & 0x80000000u) ? ~u : (u | 0x80000000u);
}

// ---------------- init: zero encoder state, xeT = start_emb ----------------
__global__ void k_init(float* hTe, float* cTe, float* xeT, const float* start_emb){
    int i = blockIdx.x*256 + threadIdx.x;
    int stride = gridDim.x*256;
    for (int j = i; j < 2*2*DENC*B_SZ; j += stride) hTe[j] = 0.f;
    for (int j = i; j < 2*DENC*B_SZ;   j += stride) cTe[j] = 0.f;
    for (int j = i; j < DEMB*B_SZ;     j += stride) xeT[j] = start_emb[j >> 6];
}

// ---------------- embedding: xT[t][k][b] = tok_emb[nx[b][t]][k] ----------------
__global__ void k_embed(const int* nx, const float* tok_emb, float* xT){
    int t = blockIdx.x;
    for (int j = threadIdx.x; j < B_SZ*DEMB; j += 256){
        int b = j >> 7; int k = j & 127;
        int row = nx[b*L_SEQ + t];
        xT[(t*DEMB + k)*B_SZ + b] = tok_emb[(size_t)row*DEMB + k];
    }
}

// ---------------- encoder input pre-gates: GpreT[dir][t][row][b] ----------------
// wave owns 16 consecutive gate-rows for one (dir,t): activations loaded once,
// W rows via wave-uniform scalar float4 loads.
__global__ void __launch_bounds__(256) k_pregates(
        const float* __restrict__ xT, const float* __restrict__ Wf, const float* __restrict__ bf,
        const float* __restrict__ Wb, const float* __restrict__ bb, float* __restrict__ GpreT){
    int wid  = (blockIdx.x*256 + threadIdx.x) >> 6;   // 2048 waves
    int lane = threadIdx.x & 63;
    for (int job = wid; job < 2*L_SEQ*64; job += 2048){  // (dir, t, rowgroup16)
        int dir = rfl(job >> 12);
        int rem = job & 4095;
        int t   = rfl(rem >> 6);
        int n0  = rfl((rem & 63) << 4);
        const float* W = (dir ? Wb : Wf) + (size_t)n0*DEMB;
        const float* bias = dir ? bb : bf;
        float acc[16];
        #pragma unroll
        for (int j = 0; j < 16; ++j) acc[j] = bias[n0 + j];
        const float* xr = xT + (size_t)t*DEMB*B_SZ + lane;
        for (int k4 = 0; k4 < DEMB/4; ++k4){
            float h0 = xr[(k4*4+0)*B_SZ], h1 = xr[(k4*4+1)*B_SZ];
            float h2 = xr[(k4*4+2)*B_SZ], h3 = xr[(k4*4+3)*B_SZ];
            #pragma unroll
            for (int j = 0; j < 16; ++j){
                float4 w = *(const float4*)(W + (size_t)j*DEMB + k4*4);
                acc[j] += w.x*h0 + w.y*h1 + w.z*h2 + w.w*h3;
            }
        }
        float* gp = GpreT + ((size_t)(dir*L_SEQ + t)*1024 + n0)*B_SZ + lane;
        #pragma unroll
        for (int j = 0; j < 16; ++j) gp[j*B_SZ] = acc[j];
    }
}

// ---------------- one encoder LSTM step (both directions) ----------------
__global__ void k_enc_step(int s, const float* __restrict__ GpreT,
                           const float* __restrict__ Whh_f, const float* __restrict__ Whh_b,
                           float* hTe, float* cTe, float* memT){
    int wid  = blockIdx.x;              // 512 blocks x 64 threads
    int lane = threadIdx.x & 63;
    int dir = rfl(wid >> 8);
    int u   = rfl(wid & 255);
    int tpre = dir ? (63 - s) : s;
    const float* Gp = GpreT + (size_t)(dir*L_SEQ + tpre)*1024*B_SZ;
    float gi = Gp[(u      )*B_SZ + lane];
    float gf = Gp[(u + 256)*B_SZ + lane];
    float gg = Gp[(u + 512)*B_SZ + lane];
    float go = Gp[(u + 768)*B_SZ + lane];
    const float* hT  = hTe + (size_t)(s&1)*(2*DENC*B_SZ) + dir*DENC*B_SZ;
    float*       hTn = hTe + (size_t)((s+1)&1)*(2*DENC*B_SZ) + dir*DENC*B_SZ;
    const float* W = dir ? Whh_b : Whh_f;
    const float4* Wi = (const float4*)(W + (size_t)(u      )*DENC);
    const float4* Wf = (const float4*)(W + (size_t)(u + 256)*DENC);
    const float4* Wg = (const float4*)(W + (size_t)(u + 512)*DENC);
    const float4* Wo = (const float4*)(W + (size_t)(u + 768)*DENC);
    #pragma unroll 4
    for (int k4 = 0; k4 < DENC/4; ++k4){
        float4 wi = Wi[k4], wf = Wf[k4], wg = Wg[k4], wo = Wo[k4];
        const float* hp = hT + k4*4*B_SZ + lane;
        float h0 = hp[0], h1 = hp[B_SZ], h2 = hp[2*B_SZ], h3 = hp[3*B_SZ];
        gi += wi.x*h0 + wi.y*h1 + wi.z*h2 + wi.w*h3;
        gf += wf.x*h0 + wf.y*h1 + wf.z*h2 + wf.w*h3;
        gg += wg.x*h0 + wg.y*h1 + wg.z*h2 + wg.w*h3;
        go += wo.x*h0 + wo.y*h1 + wo.z*h2 + wo.w*h3;
    }
    float c  = cTe[(dir*DENC + u)*B_SZ + lane];
    float cn = sigm(gf)*c + sigm(gi)*tanhf(gg);
    float hn = sigm(go)*tanhf(cn);
    cTe[(dir*DENC + u)*B_SZ + lane] = cn;
    hTn[u*B_SZ + lane] = hn;
    int tmem = dir ? (63 - s) : s;
    memT[((size_t)tmem*DDEC + dir*DENC + u)*B_SZ + lane] = hn;
}

// ---------------- h0 = tanh(cat(hf,hb) @ transfer_W^T);  c0 = style_emb[label] ----------------
__global__ void k_h0(const float* hTe, const float* transfer_W, const float* style_emb,
                     const int* label, float* hTd, float* cTd){
    int u    = rfl((int)blockIdx.x);    // 512 blocks x 64 threads
    int lane = threadIdx.x & 63;
    const float* hf = hTe;                    // buf0 dir0 (final fwd h)
    const float* hb = hTe + DENC*B_SZ;        // buf0 dir1 (final bwd h)
    float acc = 0.f;
    const float4* W4 = (const float4*)(transfer_W + (size_t)u*DDEC);
    #pragma unroll 4
    for (int k4 = 0; k4 < 64; ++k4){
        float4 w = W4[k4];
        const float* hp = hf + k4*4*B_SZ + lane;
        acc += w.x*hp[0] + w.y*hp[B_SZ] + w.z*hp[2*B_SZ] + w.w*hp[3*B_SZ];
    }
    #pragma unroll 4
    for (int k4 = 64; k4 < 128; ++k4){
        float4 w = W4[k4];
        const float* hp = hb + (k4-64)*4*B_SZ + lane;
        acc += w.x*hp[0] + w.y*hp[B_SZ] + w.z*hp[2*B_SZ] + w.w*hp[3*B_SZ];
    }
    hTd[u*B_SZ + lane] = tanhf(acc);
    cTd[u*B_SZ + lane] = style_emb[(size_t)label[lane]*DDEC + u];
}

// ---------------- K/V precompute:  kT[b][h][d][l],  vv[b][h][l][d] ----------------
// wave owns 16 consecutive rows for one t (memT activations amortized 16x).
__global__ void __launch_bounds__(256) k_kv(
        const float* __restrict__ memT, const float* __restrict__ attn_in_w,
        const float* __restrict__ attn_in_b, float* __restrict__ kT, float* __restrict__ vv){
    int wid  = (blockIdx.x*256 + threadIdx.x) >> 6;   // 2048 waves
    int lane = threadIdx.x & 63;
    for (int job = wid; job < L_SEQ*64; job += 2048){  // (t, rowgroup16) of 1024 rows
        int t  = rfl(job >> 6);
        int n0 = rfl((job & 63) << 4);
        int wrow0 = 512 + n0;             // rows 512..1535 of attn_in_w are Wk;Wv
        const float* W = attn_in_w + (size_t)wrow0*DDEC;
        float acc[16];
        #pragma unroll
        for (int j = 0; j < 16; ++j) acc[j] = attn_in_b[wrow0 + j];
        const float* mp = memT + (size_t)t*DDEC*B_SZ + lane;
        for (int k4 = 0; k4 < DDEC/4; ++k4){
            float h0 = mp[(k4*4+0)*B_SZ], h1 = mp[(k4*4+1)*B_SZ];
            float h2 = mp[(k4*4+2)*B_SZ], h3 = mp[(k4*4+3)*B_SZ];
            #pragma unroll
            for (int j = 0; j < 16; ++j){
                float4 w = *(const float4*)(W + (size_t)j*DDEC + k4*4);
                acc[j] += w.x*h0 + w.y*h1 + w.z*h2 + w.w*h3;
            }
        }
        if (n0 < 512){                    // K rows: kT[b][h][d][t], d = n0..n0+15
            int h = n0 >> 6, d0 = n0 & 63;
            float* kp = kT + (((size_t)lane*NHD + h)*HDIM + d0)*L_SEQ + t;
            #pragma unroll
            for (int j = 0; j < 16; ++j) kp[j*L_SEQ] = acc[j];
        } else {                          // V rows: vv[b][h][t][d], d contiguous
            int r2 = n0 - 512; int h = r2 >> 6, d0 = r2 & 63;
            float* vp = vv + (((size_t)lane*NHD + h)*L_SEQ + t)*HDIM + d0;
            #pragma unroll
            for (int j4 = 0; j4 < 4; ++j4){
                float4 o; o.x = acc[j4*4]; o.y = acc[j4*4+1]; o.z = acc[j4*4+2]; o.w = acc[j4*4+3];
                *(float4*)(vp + j4*4) = o;
            }
        }
    }
}

// ---------------- decoder LSTM cell (gates + state) ----------------
__global__ void k_gates(const float* __restrict__ xeT, const float* __restrict__ hTd, float* cTd,
                        const float* __restrict__ Wih, const float* __restrict__ Whh,
                        const float* __restrict__ bias, float* h_row){
    int u    = rfl((int)blockIdx.x);    // 512 blocks x 64 threads
    int lane = threadIdx.x & 63;
    float gi = bias[u], gf = bias[u+512], gg = bias[u+1024], go = bias[u+1536];
    {
        const float4* Wi = (const float4*)(Wih + (size_t)(u       )*DEMB);
        const float4* Wf = (const float4*)(Wih + (size_t)(u + 512 )*DEMB);
        const float4* Wg = (const float4*)(Wih + (size_t)(u + 1024)*DEMB);
        const float4* Wo = (const float4*)(Wih + (size_t)(u + 1536)*DEMB);
        #pragma unroll 4
        for (int k4 = 0; k4 < DEMB/4; ++k4){
            float4 wi = Wi[k4], wf = Wf[k4], wg = Wg[k4], wo = Wo[k4];
            const float* hp = xeT + k4*4*B_SZ + lane;
            float h0 = hp[0], h1 = hp[B_SZ], h2 = hp[2*B_SZ], h3 = hp[3*B_SZ];
            gi += wi.x*h0 + wi.y*h1 + wi.z*h2 + wi.w*h3;
            gf += wf.x*h0 + wf.y*h1 + wf.z*h2 + wf.w*h3;
            gg += wg.x*h0 + wg.y*h1 + wg.z*h2 + wg.w*h3;
            go += wo.x*h0 + wo.y*h1 + wo.z*h2 + wo.w*h3;
        }
    }
    {
        const float4* Wi = (const float4*)(Whh + (size_t)(u       )*DDEC);
        const float4* Wf = (const float4*)(Whh + (size_t)(u + 512 )*DDEC);
        const float4* Wg = (const float4*)(Whh + (size_t)(u + 1024)*DDEC);
        const float4* Wo = (const float4*)(Whh + (size_t)(u + 1536)*DDEC);
        #pragma unroll 4
        for (int k4 = 0; k4 < DDEC/4; ++k4){
            float4 wi = Wi[k4], wf = Wf[k4], wg = Wg[k4], wo = Wo[k4];
            const float* hp = hTd + k4*4*B_SZ + lane;
            float h0 = hp[0], h1 = hp[B_SZ], h2 = hp[2*B_SZ], h3 = hp[3*B_SZ];
            gi += wi.x*h0 + wi.y*h1 + wi.z*h2 + wi.w*h3;
            gf += wf.x*h0 + wf.y*h1 + wf.z*h2 + wf.w*h3;
            gg += wg.x*h0 + wg.y*h1 + wg.z*h2 + wg.w*h3;
            go += wo.x*h0 + wo.y*h1 + wo.z*h2 + wo.w*h3;
        }
    }
    float c  = cTd[u*B_SZ + lane];
    float cn = sigm(gf)*c + sigm(gi)*tanhf(gg);
    float h_ = sigm(go)*tanhf(cn);
    cTd[u*B_SZ + lane] = cn;
    h_row[(size_t)lane*DDEC + u] = h_;
}

// ---------------- attention + output proj + residual + LayerNorm (one WG per batch) ----------------
__global__ void __launch_bounds__(256) k_attn(
        const float* __restrict__ h_row, const float* __restrict__ kT, const float* __restrict__ vv,
        const float* __restrict__ attn_in_w, const float* __restrict__ attn_in_b,
        const float* __restrict__ attn_out_w, const float* __restrict__ attn_out_b,
        const float* __restrict__ ln_g, const float* __restrict__ ln_b,
        float* hTd, float* hLN_row){
    int b = blockIdx.x, tid = threadIdx.x;
    __shared__ float hs[512], qs[512], ss[512], cx[512], ys[512];
    __shared__ float ssum[8];
    __shared__ float red[256];
    hs[tid]     = h_row[(size_t)b*512 + tid];
    hs[tid+256] = h_row[(size_t)b*512 + tid + 256];
    __syncthreads();
    // q = (h_ @ Wq^T + bq) * scale
    for (int r = 0; r < 2; ++r){
        int row = tid + r*256;
        float acc = attn_in_b[row];
        const float4* W4 = (const float4*)(attn_in_w + (size_t)row*512);
        #pragma unroll 4
        for (int k4 = 0; k4 < 128; ++k4){
            float4 w = W4[k4];
            acc += w.x*hs[k4*4] + w.y*hs[k4*4+1] + w.z*hs[k4*4+2] + w.w*hs[k4*4+3];
        }
        qs[row] = acc * 0.125f;
    }
    __syncthreads();
    // scores[h][l] = q[h]·k[l]
    for (int r = 0; r < 2; ++r){
        int job = tid + r*256; int h = job >> 6, l = job & 63;
        const float* kp = kT + ((size_t)b*NHD + h)*HDIM*L_SEQ + l;
        float acc = 0.f;
        #pragma unroll 8
        for (int d = 0; d < 64; ++d) acc += qs[h*64 + d] * kp[d*64];
        ss[job] = acc;
    }
    __syncthreads();
    if (tid < 8){
        float m = -1e30f;
        for (int l = 0; l < 64; ++l) m = fmaxf(m, ss[tid*64 + l]);
        float s = 0.f;
        for (int l = 0; l < 64; ++l){ float e = expf(ss[tid*64 + l] - m); ss[tid*64 + l] = e; s += e; }
        ssum[tid] = s;
    }
    __syncthreads();
    // ctx[h][d] = sum_l att * v
    for (int r = 0; r < 2; ++r){
        int job = tid + r*256; int h = job >> 6, d = job & 63;
        const float* vp = vv + ((size_t)b*NHD + h)*L_SEQ*HDIM + d;
        float acc = 0.f;
        #pragma unroll 8
        for (int l = 0; l < 64; ++l) acc += ss[h*64 + l] * vp[l*HDIM];
        cx[job] = acc / ssum[h];
    }
    __syncthreads();
    // a = ctx @ attn_out^T + b ; y = h_ + a
    for (int r = 0; r < 2; ++r){
        int row = tid + r*256;
        float acc = attn_out_b[row];
        const float4* W4 = (const float4*)(attn_out_w + (size_t)row*512);
        #pragma unroll 4
        for (int k4 = 0; k4 < 128; ++k4){
            float4 w = W4[k4];
            acc += w.x*cx[k4*4] + w.y*cx[k4*4+1] + w.z*cx[k4*4+2] + w.w*cx[k4*4+3];
        }
        ys[row] = hs[row] + acc;
    }
    __syncthreads();
    // LayerNorm
    red[tid] = ys[tid] + ys[tid+256];
    __syncthreads();
    for (int off = 128; off > 0; off >>= 1){ if (tid < off) red[tid] += red[tid+off]; __syncthreads(); }
    float mu = red[0] * (1.f/512.f);
    __syncthreads();
    float d0 = ys[tid] - mu, d1 = ys[tid+256] - mu;
    red[tid] = d0*d0 + d1*d1;
    __syncthreads();
    for (int off = 128; off > 0; off >>= 1){ if (tid < off) red[tid] += red[tid+off]; __syncthreads(); }
    float rstd = 1.f / sqrtf(red[0]*(1.f/512.f) + 1e-5f);
    for (int r = 0; r < 2; ++r){
        int i = tid + r*256;
        float hv = (ys[i] - mu) * rstd * ln_g[i] + ln_b[i];
        hLN_row[(size_t)b*512 + i] = hv;
        hTd[(size_t)i*64 + b] = hv;
    }
}

// ---------------- projection: logits = h @ proj_W^T + b ; per-BLOCK argmax partials ----------------
__global__ void __launch_bounds__(256) k_proj(int t, const float* __restrict__ hTd,
                       const float* __restrict__ proj_W, const float* __restrict__ proj_b,
                       float* __restrict__ out, ull* __restrict__ partials){
    int wid  = (blockIdx.x*256 + threadIdx.x) >> 6;   // 0..1999, wave owns 16 vocab rows
    int lane = threadIdx.x & 63;                      // lane = batch
    int wv   = threadIdx.x >> 6;
    int n0 = rfl(wid << 4);
    float acc[16];
    #pragma unroll
    for (int j = 0; j < 16; ++j) acc[j] = proj_b[n0 + j];
    const float* W = proj_W + (size_t)n0*DDEC;
    #pragma unroll 2
    for (int k4 = 0; k4 < 128; ++k4){
        float h0 = hTd[(k4*4+0)*B_SZ + lane];
        float h1 = hTd[(k4*4+1)*B_SZ + lane];
        float h2 = hTd[(k4*4+2)*B_SZ + lane];
        float h3 = hTd[(k4*4+3)*B_SZ + lane];
        #pragma unroll
        for (int j = 0; j < 16; ++j){
            float4 w = *(const float4*)(W + (size_t)j*DDEC + k4*4);
            acc[j] += w.x*h0 + w.y*h1 + w.z*h2 + w.w*h3;
        }
    }
    ull m = 0;
    float* op = out + (size_t)lane*(TDEC*VSZ) + (size_t)t*VSZ + n0;
    #pragma unroll
    for (int j4 = 0; j4 < 4; ++j4){
        float4 o; o.x = acc[j4*4]; o.y = acc[j4*4+1]; o.z = acc[j4*4+2]; o.w = acc[j4*4+3];
        *(float4*)(op + j4*4) = o;
        #pragma unroll
        for (int j = j4*4; j < j4*4+4; ++j){
            ull p = ((ull)fmono(acc[j]) << 32) | (unsigned)(~(unsigned)(n0 + j));
            m = (p > m) ? p : m;
        }
    }
    __shared__ ull red[4][64];
    red[wv][lane] = m;
    __syncthreads();
    if (wv == 0){
        ull a = red[0][lane], b2 = red[1][lane], c = red[2][lane], d = red[3][lane];
        if (b2 > a) a = b2; if (c > a) a = c; if (d > a) a = d;
        partials[(size_t)lane*512 + blockIdx.x] = a;
    }
}

// ---------------- argmax finalize + greedy-feedback embedding: xeT[k][b] ----------------
__global__ void k_fin(const ull* __restrict__ partials, const float* __restrict__ tok_emb, float* xeT){
    int b = blockIdx.x, tid = threadIdx.x;   // 128 threads
    __shared__ ull red[128];
    __shared__ int sidx;
    ull m = 0;
    for (int j = tid; j < 500; j += 128){
        ull p = partials[(size_t)b*512 + j];
        if (p > m) m = p;
    }
    red[tid] = m; __syncthreads();
    for (int off = 64; off > 0; off >>= 1){
        if (tid < off){ if (red[tid+off] > red[tid]) red[tid] = red[tid+off]; }
        __syncthreads();
    }
    if (tid == 0) sidx = (int)(~(unsigned)(red[0] & 0xffffffffull));
    __syncthreads();
    int idx = sidx;
    xeT[tid*B_SZ + b] = tok_emb[(size_t)idx*DEMB + tid];
}

extern "C" void kernel_launch(void* const* d_in, const int* in_sizes, int n_in,
                              void* d_out, int out_size, void* d_ws, size_t ws_size,
                              hipStream_t stream){
    (void)in_sizes; (void)n_in; (void)out_size; (void)ws_size;
    const int*   nx        = (const int*)d_in[0];
    const int*   label     = (const int*)d_in[1];
    const float* start_emb = (const float*)d_in[2];
    const float* tok_emb   = (const float*)d_in[3];
    const float* style_emb = (const float*)d_in[4];
    const float* enc_Wih_f = (const float*)d_in[5];
    const float* enc_Whh_f = (const float*)d_in[6];
    const float* enc_b_f   = (const float*)d_in[7];
    const float* enc_Wih_b = (const float*)d_in[8];
    const float* enc_Whh_b = (const float*)d_in[9];
    const float* enc_b_b   = (const float*)d_in[10];
    const float* transfer_W= (const float*)d_in[11];
    const float* dec_Wih   = (const float*)d_in[12];
    const float* dec_Whh   = (const float*)d_in[13];
    const float* dec_b     = (const float*)d_in[14];
    const float* attn_in_w = (const float*)d_in[15];
    const float* attn_in_b = (const float*)d_in[16];
    const float* attn_out_w= (const float*)d_in[17];
    const float* attn_out_b= (const float*)d_in[18];
    const float* proj_W    = (const float*)d_in[19];
    const float* proj_b    = (const float*)d_in[20];
    const float* ln_g      = (const float*)d_in[21];
    const float* ln_b      = (const float*)d_in[22];
    float* out = (float*)d_out;
    float* ws  = (float*)d_ws;

    size_t off = 0;
    float* xT    = ws + off; off += (size_t)L_SEQ*DEMB*B_SZ;        // 524288
    float* GpreT = ws + off; off += (size_t)2*L_SEQ*1024*B_SZ;      // 8388608
    float* memT  = ws + off; off += (size_t)L_SEQ*DDEC*B_SZ;        // 2097152
    float* kT    = ws + off; off += (size_t)B_SZ*NHD*HDIM*L_SEQ;    // 2097152
    float* vv    = ws + off; off += (size_t)B_SZ*NHD*L_SEQ*HDIM;    // 2097152
    float* hTe   = ws + off; off += 2*2*DENC*B_SZ;
    float* cTe   = ws + off; off += 2*DENC*B_SZ;
    float* hTd   = ws + off; off += DDEC*B_SZ;
    float* cTd   = ws + off; off += DDEC*B_SZ;
    float* h_row = ws + off; off += B_SZ*DDEC;
    float* hLN   = ws + off; off += B_SZ*DDEC;
    float* xeT   = ws + off; off += DEMB*B_SZ;
    ull* partials = (ull*)(ws + off); off += (size_t)B_SZ*512*2;

    k_init<<<64, 256, 0, stream>>>(hTe, cTe, xeT, start_emb);
    k_embed<<<64, 256, 0, stream>>>(nx, tok_emb, xT);
    k_pregates<<<512, 256, 0, stream>>>(xT, enc_Wih_f, enc_b_f, enc_Wih_b, enc_b_b, GpreT);
    for (int s = 0; s < 64; ++s)
        k_enc_step<<<512, 64, 0, stream>>>(s, GpreT, enc_Whh_f, enc_Whh_b, hTe, cTe, memT);
    k_h0<<<512, 64, 0, stream>>>(hTe, transfer_W, style_emb, label, hTd, cTd);
    k_kv<<<512, 256, 0, stream>>>(memT, attn_in_w, attn_in_b, kT, vv);
    for (int t = 0; t < 32; ++t){
        k_gates<<<512, 64, 0, stream>>>(xeT, hTd, cTd, dec_Wih, dec_Whh, dec_b, h_row);
        k_attn<<<64, 256, 0, stream>>>(h_row, kT, vv, attn_in_w, attn_in_b,
                                       attn_out_w, attn_out_b, ln_g, ln_b, hTd, hLN);
        k_proj<<<500, 256, 0, stream>>>(t, hTd, proj_W, proj_b, out, partials);
        k_fin<<<64, 128, 0, stream>>>(partials, tok_emb, xeT);
    }
}